// Round 13
// baseline (498.390 us; speedup 1.0000x reference)
//
#include <hip/hip_runtime.h>
#include <hip/hip_fp16.h>
#include <math.h>

#define N_NODES 100000
#define N_EDGES 1200000
#define SLOTS   48                              // Poisson(12): P(any deg>48) ~ 3e-10
#define LAYER_BLOCKS (N_NODES / 32)             // 3125: 8 waves, 4 nodes/wave

// ---------------------------------------------------------------- utilities

__device__ __forceinline__ float bcastf(float v, int l) {
    return __uint_as_float(__builtin_amdgcn_readlane(__float_as_uint(v), (unsigned)l));
}

__global__ __launch_bounds__(256) void zero_u32(unsigned* __restrict__ p, int n) {
    int i = blockIdx.x * 256 + threadIdx.x;
    if (i < n) p[i] = 0u;
}

// ---------------------------------------------------------------- adjacency build
// Slot-array (R11: no scan/fill needed; layout proven cost-neutral for gather).
// 8 edges/thread: batched loads -> 8 independent atomics -> 8 stores.
__global__ __launch_bounds__(256) void hist_scatter8(const int* __restrict__ src,
                                                     const int* __restrict__ dst,
                                                     unsigned* __restrict__ cnt,
                                                     unsigned* __restrict__ slots) {
    const int base = blockIdx.x * 2048 + threadIdx.x;
    int dd[8], ss[8];
    bool ok[8];
#pragma unroll
    for (int t = 0; t < 8; ++t) {
        const int e = base + t * 256;
        ok[t] = e < N_EDGES;
        dd[t] = ok[t] ? dst[e] : 0;
        ss[t] = ok[t] ? src[e] : 0;
    }
    unsigned r[8];
#pragma unroll
    for (int t = 0; t < 8; ++t)
        if (ok[t]) r[t] = atomicAdd(&cnt[dd[t]], 1u);
#pragma unroll
    for (int t = 0; t < 8; ++t)
        if (ok[t] && r[t] < SLOTS) slots[(size_t)dd[t] * SLOTS + r[t]] = (unsigned)ss[t];
}

__global__ __launch_bounds__(256) void invcnt_kernel(const unsigned* __restrict__ cnt,
                                                     float* __restrict__ invcnt) {
    int i = blockIdx.x * 256 + threadIdx.x;
    if (i < N_NODES) invcnt[i] = 1.0f / (float)(cnt[i] + 1u);   // +1 self loop
}

// ---------------------------------------------------------------- weight folding
// V2 = W @ U_bot [IN,64];  cp = c + b @ U_bot [64]
template <int IN>
__global__ __launch_bounds__(256) void precompute_v(const float* __restrict__ W,
                                                    const float* __restrict__ b,
                                                    const float* __restrict__ U,
                                                    const float* __restrict__ c,
                                                    float* __restrict__ V2,
                                                    float* __restrict__ cp) {
    __shared__ float Ub[64 * 64];
    const int tid = threadIdx.x;
    for (int j = tid; j < 64 * 64; j += 256) Ub[j] = U[IN * 64 + j];
    __syncthreads();
    const int w = tid >> 6, lane = tid & 63;
    const int r = blockIdx.x * 4 + w;
    if (r > IN) return;
    const float wv = (r < IN) ? W[r * 64 + lane] : b[lane];
    float o = (r < IN) ? 0.f : c[lane];
#pragma unroll 8
    for (int k = 0; k < 64; ++k) o += bcastf(wv, k) * Ub[k * 64 + lane];
    if (r < IN) V2[r * 64 + lane] = o;
    else        cp[lane] = o;
}

// ---------------------------------------------------------------- layer 1
// h1 = relu(x@Utop + m@V2 + cp), x fp32 [N,5] (L2-resident); OUTPUT fp16.
__global__ __launch_bounds__(512) void layer1_kernel(
        const float* __restrict__ x,
        const unsigned* __restrict__ slots,
        const unsigned* __restrict__ cnt,
        const float* __restrict__ invcnt,
        const float* __restrict__ Utop,
        const float* __restrict__ V2,
        const float* __restrict__ cp,
        __half* __restrict__ h16next) {
    constexpr int IN = 5;
    __shared__ float2 T[IN * 64];
    __shared__ float2 A2[32 * IN];
    const int tid = threadIdx.x;
    for (int j = tid; j < IN * 64; j += 512) T[j] = make_float2(Utop[j], V2[j]);
    const int wv = __builtin_amdgcn_readfirstlane(tid >> 6);
    const int lane = tid & 63;
    const int n0 = blockIdx.x * 32 + wv * 4;

    for (int i = 0; i < 4; ++i) {
        const int n = n0 + i;
        int deg = (int)cnt[n]; if (deg > SLOTS) deg = SLOTS;
        const size_t sb = (size_t)n * SLOTS;
        const float hp = (lane < IN) ? x[(size_t)n * IN + lane] : 0.f;
        float m = hp;
        int j = 0;
        for (; j + 8 <= deg; j += 8) {
            const unsigned i0 = slots[sb + j + 0], i1 = slots[sb + j + 1];
            const unsigned i2 = slots[sb + j + 2], i3 = slots[sb + j + 3];
            const unsigned i4 = slots[sb + j + 4], i5 = slots[sb + j + 5];
            const unsigned i6 = slots[sb + j + 6], i7 = slots[sb + j + 7];
            const float a0 = (lane < IN) ? x[(size_t)i0 * IN + lane] : 0.f;
            const float a1 = (lane < IN) ? x[(size_t)i1 * IN + lane] : 0.f;
            const float a2 = (lane < IN) ? x[(size_t)i2 * IN + lane] : 0.f;
            const float a3 = (lane < IN) ? x[(size_t)i3 * IN + lane] : 0.f;
            const float a4 = (lane < IN) ? x[(size_t)i4 * IN + lane] : 0.f;
            const float a5 = (lane < IN) ? x[(size_t)i5 * IN + lane] : 0.f;
            const float a6 = (lane < IN) ? x[(size_t)i6 * IN + lane] : 0.f;
            const float a7 = (lane < IN) ? x[(size_t)i7 * IN + lane] : 0.f;
            m += ((a0 + a1) + (a2 + a3)) + ((a4 + a5) + (a6 + a7));
        }
        for (; j < deg; ++j) {
            const unsigned i0 = slots[sb + j];
            m += (lane < IN) ? x[(size_t)i0 * IN + lane] : 0.f;
        }
        if (lane < IN) A2[(wv * 4 + i) * IN + lane] = make_float2(hp, m * invcnt[n]);
    }
    __syncthreads();

    const float cpl = cp[lane];
    float acc0 = cpl, acc1 = cpl, acc2 = cpl, acc3 = cpl;
    const int ab = wv * 4 * IN;
#pragma unroll
    for (int k = 0; k < IN; ++k) {
        const float2 t = T[k * 64 + lane];
        const float2 a0 = A2[ab + k];
        const float2 a1 = A2[ab + IN + k];
        const float2 a2 = A2[ab + 2 * IN + k];
        const float2 a3 = A2[ab + 3 * IN + k];
        acc0 += a0.x * t.x + a0.y * t.y;
        acc1 += a1.x * t.x + a1.y * t.y;
        acc2 += a2.x * t.x + a2.y * t.y;
        acc3 += a3.x * t.x + a3.y * t.y;
    }
    const size_t o0 = (size_t)n0 * 64 + lane;
    h16next[o0]       = __float2half(fmaxf(acc0, 0.f));
    h16next[o0 + 64]  = __float2half(fmaxf(acc1, 0.f));
    h16next[o0 + 128] = __float2half(fmaxf(acc2, 0.f));
    h16next[o0 + 192] = __float2half(fmaxf(acc3, 0.f));
}

// ---------------------------------------------------------------- layers 2/3
// fp16 input rows (128 B): 32 lanes x half2 per row -> 2 edges per load
// instruction, 8-deep unroll = 16 edges in flight/wave. Accumulate fp32,
// fold edge-halves with shfl_xor(32). Layer 2: fp16 output. Layer 3: fp32
// output to d_out + fused heads.
template <bool HEADS>
__global__ __launch_bounds__(512) void fused_layer16(
        const __half* __restrict__ h16prev,
        const unsigned* __restrict__ slots,
        const unsigned* __restrict__ cnt,
        const float* __restrict__ invcnt,
        const float* __restrict__ Utop,
        const float* __restrict__ V2,
        const float* __restrict__ cp,
        __half* __restrict__ h16next,          // layer 2 path
        float* __restrict__ hout,              // layer 3 path
        const float* __restrict__ Ws,  const float* __restrict__ bs,
        const float* __restrict__ Wst, const float* __restrict__ bst,
        const float* __restrict__ Wo,  const float* __restrict__ bo,
        float* __restrict__ state, float* __restrict__ part) {
    __shared__ float2 T[64 * 64];     // (Utop[k][lane], V2[k][lane])  32 KiB
    __shared__ float2 A2[32 * 64];    // (hp[k], m[k]) per local node  16 KiB
    __shared__ float red[8][2];
    const int tid = threadIdx.x;
    for (int j = tid; j < 64 * 64; j += 512) T[j] = make_float2(Utop[j], V2[j]);
    const int wv = __builtin_amdgcn_readfirstlane(tid >> 6);   // uniform wave id
    const int lane = tid & 63;
    const int g = lane >> 5, q = lane & 31;    // edge-half, feature-pair
    const int n0 = blockIdx.x * 32 + wv * 4;
    const __half2* H2 = (const __half2*)h16prev;   // row stride = 32 half2

    // ---- phase 1: half2 gather, 2 edges/instruction, 16 edges in flight
    for (int i = 0; i < 4; ++i) {
        const int n = n0 + i;
        int deg = (int)cnt[n]; if (deg > SLOTS) deg = SLOTS;
        const size_t sb = (size_t)n * SLOTS;
        float mx = 0.f, my = 0.f;
        int j = 0;
        for (; j + 16 <= deg; j += 16) {
            __half2 v[8];
#pragma unroll
            for (int t = 0; t < 8; ++t) {
                const unsigned idx = slots[sb + j + 2 * t + g];
                v[t] = H2[(size_t)idx * 32 + q];
            }
#pragma unroll
            for (int t = 0; t < 8; ++t) {
                const float2 f = __half22float2(v[t]);
                mx += f.x; my += f.y;
            }
        }
        for (; j < deg; j += 2) {                      // remainder, 2 edges/pass
            const bool val = (j + g) < deg;
            const unsigned idx = val ? slots[sb + j + g] : (unsigned)n;
            const float2 f = __half22float2(H2[(size_t)idx * 32 + q]);
            mx += val ? f.x : 0.f;
            my += val ? f.y : 0.f;
        }
        // fold the two edge-halves
        mx += __shfl_xor(mx, 32);
        my += __shfl_xor(my, 32);
        // self row + mean
        const float2 hp = __half22float2(H2[(size_t)n * 32 + q]);
        const float iv = invcnt[n];
        if (g == 0) {
            float4* a = (float4*)&A2[(wv * 4 + i) * 64 + 2 * q];
            *a = make_float4(hp.x, (mx + hp.x) * iv, hp.y, (my + hp.y) * iv);
        }
    }
    __syncthreads();

    // ---- phase 2: 4-node register-tile GEMM (fp32)
    const float cpl = cp[lane];
    float acc0 = cpl, acc1 = cpl, acc2 = cpl, acc3 = cpl;
    const int ab = wv * 4 * 64;
#pragma unroll 8
    for (int k = 0; k < 64; ++k) {
        const float2 t = T[k * 64 + lane];
        const float2 a0 = A2[ab + k];               // uniform addr -> LDS broadcast
        const float2 a1 = A2[ab + 64 + k];
        const float2 a2 = A2[ab + 128 + k];
        const float2 a3 = A2[ab + 192 + k];
        acc0 += a0.x * t.x + a0.y * t.y;
        acc1 += a1.x * t.x + a1.y * t.y;
        acc2 += a2.x * t.x + a2.y * t.y;
        acc3 += a3.x * t.x + a3.y * t.y;
    }
    const float h0 = fmaxf(acc0, 0.f), h1 = fmaxf(acc1, 0.f);
    const float h2 = fmaxf(acc2, 0.f), h3 = fmaxf(acc3, 0.f);
    const size_t o0 = (size_t)n0 * 64 + lane;
    if constexpr (!HEADS) {
        h16next[o0]       = __float2half(h0);
        h16next[o0 + 64]  = __float2half(h1);
        h16next[o0 + 128] = __float2half(h2);
        h16next[o0 + 192] = __float2half(h3);
    } else {
        hout[o0]       = h0;
        hout[o0 + 64]  = h1;
        hout[o0 + 128] = h2;
        hout[o0 + 192] = h3;
        const float ws0 = Ws[lane * 2], ws1 = Ws[lane * 2 + 1];
        const float wst = Wst[lane],    wo  = Wo[lane];
        float r[16];
        r[0]  = h0 * ws0; r[1]  = h0 * ws1; r[2]  = h0 * wst; r[3]  = h0 * wo;
        r[4]  = h1 * ws0; r[5]  = h1 * ws1; r[6]  = h1 * wst; r[7]  = h1 * wo;
        r[8]  = h2 * ws0; r[9]  = h2 * ws1; r[10] = h2 * wst; r[11] = h2 * wo;
        r[12] = h3 * ws0; r[13] = h3 * ws1; r[14] = h3 * wst; r[15] = h3 * wo;
#pragma unroll
        for (int off = 1; off < 64; off <<= 1)
#pragma unroll
            for (int t = 0; t < 16; ++t) r[t] += __shfl_xor(r[t], off);
        if (lane == 0) {
            const float bs0 = bs[0], bs1 = bs[1], bt = bst[0], b0 = bo[0];
            float sg = 0.f, oc = 0.f;
#pragma unroll
            for (int i = 0; i < 4; ++i) {
                const size_t n = (size_t)(n0 + i);
                state[n * 2 + 0] = r[i * 4 + 0] + bs0;
                state[n * 2 + 1] = r[i * 4 + 1] + bs1;
                sg += 1.0f / (1.0f + __expf(-(r[i * 4 + 2] + bt)));
                oc += r[i * 4 + 3] + b0;
            }
            red[wv][0] = sg; red[wv][1] = oc;
        }
        __syncthreads();
        if (tid == 0) {
            float a = 0.f, b2 = 0.f;
#pragma unroll
            for (int w = 0; w < 8; ++w) { a += red[w][0]; b2 += red[w][1]; }
            part[blockIdx.x * 2 + 0] = a;
            part[blockIdx.x * 2 + 1] = b2;
        }
    }
}

// ---------------------------------------------------------------- final reduce

__global__ __launch_bounds__(1024) void final_reduce(const float* __restrict__ part,
                                                     float* __restrict__ scal) {
    __shared__ float l0[1024], l1[1024];
    const int t = threadIdx.x;
    float a = 0.f, b = 0.f;
    for (int i = t; i < LAYER_BLOCKS; i += 1024) { a += part[2 * i]; b += part[2 * i + 1]; }
    l0[t] = a; l1[t] = b;
    __syncthreads();
    for (int off = 512; off; off >>= 1) {
        if (t < off) { l0[t] += l0[t + off]; l1[t] += l1[t + off]; }
        __syncthreads();
    }
    if (t == 0) {
        scal[0] = l0[0] / (float)N_NODES;   // stability
        scal[1] = l1[0] / (float)N_NODES;   // opf_cost
    }
}

// ---------------------------------------------------------------- launch

extern "C" void kernel_launch(void* const* d_in, const int* in_sizes, int n_in,
                              void* d_out, int out_size, void* d_ws, size_t ws_size,
                              hipStream_t stream) {
    const float* x   = (const float*)d_in[0];
    const int*   ei  = (const int*)d_in[1];
    const float* W1  = (const float*)d_in[2];
    const float* b1  = (const float*)d_in[3];
    const float* U1  = (const float*)d_in[4];
    const float* c1  = (const float*)d_in[5];
    const float* W2  = (const float*)d_in[6];
    const float* b2  = (const float*)d_in[7];
    const float* U2  = (const float*)d_in[8];
    const float* c2  = (const float*)d_in[9];
    const float* W3  = (const float*)d_in[10];
    const float* b3  = (const float*)d_in[11];
    const float* U3  = (const float*)d_in[12];
    const float* c3  = (const float*)d_in[13];
    const float* Ws  = (const float*)d_in[14];
    const float* bs  = (const float*)d_in[15];
    const float* Wst = (const float*)d_in[16];
    const float* bst = (const float*)d_in[17];
    const float* Wo  = (const float*)d_in[18];
    const float* bo  = (const float*)d_in[19];

    const int* src = ei;              // edge_index[0]
    const int* dst = ei + N_EDGES;    // edge_index[1]

    char* wsp = (char*)d_ws;
    size_t off = 0;
    auto alloc = [&](size_t bytes) -> char* {
        char* p = wsp + off;
        off = (off + bytes + 255) & ~(size_t)255;
        return p;
    };
    unsigned* cnt    = (unsigned*)alloc((size_t)N_NODES * 4);
    float*    invcnt = (float*)   alloc((size_t)N_NODES * 4);
    float*    part   = (float*)   alloc((size_t)LAYER_BLOCKS * 2 * 4);
    float*    V2a    = (float*)   alloc((size_t)5 * 64 * 4);
    float*    V2b    = (float*)   alloc((size_t)64 * 64 * 4);
    float*    V2c    = (float*)   alloc((size_t)64 * 64 * 4);
    float*    cpa    = (float*)   alloc((size_t)64 * 4);
    float*    cpb    = (float*)   alloc((size_t)64 * 4);
    float*    cpc    = (float*)   alloc((size_t)64 * 4);
    unsigned* slots  = (unsigned*)alloc((size_t)N_NODES * SLOTS * 4);   // 19.2 MB
    __half*   h16A   = (__half*)  alloc((size_t)N_NODES * 64 * 2);      // 12.8 MB
    __half*   h16B   = (__half*)  alloc((size_t)N_NODES * 64 * 2);      // 12.8 MB

    float* out   = (float*)d_out;
    float* state = out;                 // [N, 2]
    float* scal  = out + 200000;        // stability, opf_cost
    float* hout  = out + 200002;        // [N, 64]

    const int NB  = (N_NODES + 255) / 256;   // 391
    const int EB8 = (N_EDGES + 2047) / 2048; // 586

    // weight folding (graph-independent)
    precompute_v<5> <<<2, 256, 0, stream>>>(W1, b1, U1, c1, V2a, cpa);
    precompute_v<64><<<17, 256, 0, stream>>>(W2, b2, U2, c2, V2b, cpb);
    precompute_v<64><<<17, 256, 0, stream>>>(W3, b3, U3, c3, V2c, cpc);

    // adjacency: slot array, one batched pass (no scan, no fill)
    zero_u32<<<NB, 256, 0, stream>>>(cnt, N_NODES);
    hist_scatter8<<<EB8, 256, 0, stream>>>(src, dst, cnt, slots);
    invcnt_kernel<<<NB, 256, 0, stream>>>(cnt, invcnt);

    // layers: h = relu(hp@Utop + mean@V2 + cp); fp16 h between layers
    layer1_kernel<<<LAYER_BLOCKS, 512, 0, stream>>>(
        x, slots, cnt, invcnt, U1, V2a, cpa, h16A);
    fused_layer16<false><<<LAYER_BLOCKS, 512, 0, stream>>>(
        h16A, slots, cnt, invcnt, U2, V2b, cpb, h16B, nullptr,
        nullptr, nullptr, nullptr, nullptr, nullptr, nullptr, nullptr, nullptr);
    fused_layer16<true><<<LAYER_BLOCKS, 512, 0, stream>>>(
        h16B, slots, cnt, invcnt, U3, V2c, cpc, nullptr, hout,
        Ws, bs, Wst, bst, Wo, bo, state, part);
    final_reduce<<<1, 1024, 0, stream>>>(part, scal);
}

// Round 14
// 368.488 us; speedup vs baseline: 1.3525x; 1.3525x over previous
//
#include <hip/hip_runtime.h>
#include <hip/hip_fp16.h>
#include <math.h>

#define N_NODES 100000
#define N_EDGES 1200000
#define SLOTS   48                              // Poisson(12): P(any deg>48) ~ 3e-10
#define LAYER_BLOCKS (N_NODES / 32)             // 3125: 8 waves, 4 nodes/wave

// ---------------------------------------------------------------- utilities

__device__ __forceinline__ float bcastf(float v, int l) {
    return __uint_as_float(__builtin_amdgcn_readlane(__float_as_uint(v), (unsigned)l));
}

__global__ __launch_bounds__(256) void zero_u32(unsigned* __restrict__ p, int n) {
    int i = blockIdx.x * 256 + threadIdx.x;
    if (i < n) p[i] = 0u;
}

// ---------------------------------------------------------------- adjacency build
// Slot array (R11): one batched pass, no scan/fill. 8 edges/thread:
// batched loads -> 8 independent atomics -> 8 stores.
__global__ __launch_bounds__(256) void hist_scatter8(const int* __restrict__ src,
                                                     const int* __restrict__ dst,
                                                     unsigned* __restrict__ cnt,
                                                     unsigned* __restrict__ slots) {
    const int base = blockIdx.x * 2048 + threadIdx.x;
    int dd[8], ss[8];
    bool ok[8];
#pragma unroll
    for (int t = 0; t < 8; ++t) {
        const int e = base + t * 256;
        ok[t] = e < N_EDGES;
        dd[t] = ok[t] ? dst[e] : 0;
        ss[t] = ok[t] ? src[e] : 0;
    }
    unsigned r[8];
#pragma unroll
    for (int t = 0; t < 8; ++t)
        if (ok[t]) r[t] = atomicAdd(&cnt[dd[t]], 1u);
#pragma unroll
    for (int t = 0; t < 8; ++t)
        if (ok[t] && r[t] < SLOTS) slots[(size_t)dd[t] * SLOTS + r[t]] = (unsigned)ss[t];
}

__global__ __launch_bounds__(256) void invcnt_kernel(const unsigned* __restrict__ cnt,
                                                     float* __restrict__ invcnt) {
    int i = blockIdx.x * 256 + threadIdx.x;
    if (i < N_NODES) invcnt[i] = 1.0f / (float)(cnt[i] + 1u);   // +1 self loop
}

// ---------------------------------------------------------------- weight folding
// V2 = W @ U_bot [IN,64];  cp = c + b @ U_bot [64]
template <int IN>
__global__ __launch_bounds__(256) void precompute_v(const float* __restrict__ W,
                                                    const float* __restrict__ b,
                                                    const float* __restrict__ U,
                                                    const float* __restrict__ c,
                                                    float* __restrict__ V2,
                                                    float* __restrict__ cp) {
    __shared__ float Ub[64 * 64];
    const int tid = threadIdx.x;
    for (int j = tid; j < 64 * 64; j += 256) Ub[j] = U[IN * 64 + j];
    __syncthreads();
    const int w = tid >> 6, lane = tid & 63;
    const int r = blockIdx.x * 4 + w;
    if (r > IN) return;
    const float wv = (r < IN) ? W[r * 64 + lane] : b[lane];
    float o = (r < IN) ? 0.f : c[lane];
#pragma unroll 8
    for (int k = 0; k < 64; ++k) o += bcastf(wv, k) * Ub[k * 64 + lane];
    if (r < IN) V2[r * 64 + lane] = o;
    else        cp[lane] = o;
}

// ---------------------------------------------------------------- fused layer
// h[n,:] = relu( hp@Utop + m@V2 + cp ), m = mean(self + in-neighbors).
// R11's exact gather shape (8/4/1-deep, one edge/instruction, 8 loads in
// flight at deg~12) — but IN16 rows are fp16: each lane loads 2 B (ushort),
// 128 B/row, HALF the bytes at IDENTICAL ILP (the R13 lesson).
// IN16/OUT16 select fp16 vs fp32 input/output; layer 3 adds fused heads.
template <int IN, bool IN16, bool OUT16, bool HEADS>
__global__ __launch_bounds__(512) void fused_layer(
        const float* __restrict__ hprevF,
        const __half* __restrict__ hprevH,
        const unsigned* __restrict__ slots,
        const unsigned* __restrict__ cnt,
        const float* __restrict__ invcnt,
        const float* __restrict__ Utop,
        const float* __restrict__ V2,
        const float* __restrict__ cp,
        float* __restrict__ hnextF,
        __half* __restrict__ hnextH,
        const float* __restrict__ Ws,  const float* __restrict__ bs,
        const float* __restrict__ Wst, const float* __restrict__ bst,
        const float* __restrict__ Wo,  const float* __restrict__ bo,
        float* __restrict__ state, float* __restrict__ part) {
    __shared__ float2 T[IN * 64];     // (Utop[k][lane], V2[k][lane])
    __shared__ float2 A2[32 * IN];    // (hp[k], m[k]) per local node
    __shared__ float red[8][2];
    const int tid = threadIdx.x;
    for (int j = tid; j < IN * 64; j += 512) T[j] = make_float2(Utop[j], V2[j]);
    const int wv = __builtin_amdgcn_readfirstlane(tid >> 6);   // uniform wave id
    const int lane = tid & 63;
    const int n0 = blockIdx.x * 32 + wv * 4;

    auto ldrow = [&](unsigned idx) -> float {
        if constexpr (IN16)
            return (lane < IN) ? __half2float(hprevH[(size_t)idx * IN + lane]) : 0.f;
        else
            return (lane < IN) ? hprevF[(size_t)idx * IN + lane] : 0.f;
    };

    // ---- phase 1: gather-mean, 4 nodes sequential per wave, 8 loads deep
    for (int i = 0; i < 4; ++i) {
        const int n = n0 + i;
        int deg = (int)cnt[n]; if (deg > SLOTS) deg = SLOTS;   // wave-uniform
        const size_t sb = (size_t)n * SLOTS;
        const float hp = ldrow((unsigned)n);
        float m = hp;                                          // self loop
        int j = 0;
        for (; j + 8 <= deg; j += 8) {
            const unsigned i0 = slots[sb + j + 0], i1 = slots[sb + j + 1];
            const unsigned i2 = slots[sb + j + 2], i3 = slots[sb + j + 3];
            const unsigned i4 = slots[sb + j + 4], i5 = slots[sb + j + 5];
            const unsigned i6 = slots[sb + j + 6], i7 = slots[sb + j + 7];
            const float a0 = ldrow(i0);
            const float a1 = ldrow(i1);
            const float a2 = ldrow(i2);
            const float a3 = ldrow(i3);
            const float a4 = ldrow(i4);
            const float a5 = ldrow(i5);
            const float a6 = ldrow(i6);
            const float a7 = ldrow(i7);
            m += ((a0 + a1) + (a2 + a3)) + ((a4 + a5) + (a6 + a7));
        }
        for (; j + 4 <= deg; j += 4) {
            const unsigned i0 = slots[sb + j + 0], i1 = slots[sb + j + 1];
            const unsigned i2 = slots[sb + j + 2], i3 = slots[sb + j + 3];
            const float a0 = ldrow(i0);
            const float a1 = ldrow(i1);
            const float a2 = ldrow(i2);
            const float a3 = ldrow(i3);
            m += (a0 + a1) + (a2 + a3);
        }
        for (; j < deg; ++j)
            m += ldrow(slots[sb + j]);
        if (lane < IN) A2[(wv * 4 + i) * IN + lane] = make_float2(hp, m * invcnt[n]);
    }
    __syncthreads();

    // ---- phase 2: 4-node register-tile GEMM (fp32)
    const float cpl = cp[lane];
    float acc0 = cpl, acc1 = cpl, acc2 = cpl, acc3 = cpl;
    const int ab = wv * 4 * IN;
#pragma unroll 8
    for (int k = 0; k < IN; ++k) {
        const float2 t = T[k * 64 + lane];
        const float2 a0 = A2[ab + k];               // uniform addr -> LDS broadcast
        const float2 a1 = A2[ab + IN + k];
        const float2 a2 = A2[ab + 2 * IN + k];
        const float2 a3 = A2[ab + 3 * IN + k];
        acc0 += a0.x * t.x + a0.y * t.y;
        acc1 += a1.x * t.x + a1.y * t.y;
        acc2 += a2.x * t.x + a2.y * t.y;
        acc3 += a3.x * t.x + a3.y * t.y;
    }
    const float h0 = fmaxf(acc0, 0.f), h1 = fmaxf(acc1, 0.f);
    const float h2 = fmaxf(acc2, 0.f), h3 = fmaxf(acc3, 0.f);
    const size_t o0 = (size_t)n0 * 64 + lane;
    if constexpr (OUT16) {
        hnextH[o0]       = __float2half(h0);
        hnextH[o0 + 64]  = __float2half(h1);
        hnextH[o0 + 128] = __float2half(h2);
        hnextH[o0 + 192] = __float2half(h3);
    } else {
        hnextF[o0]       = h0;
        hnextF[o0 + 64]  = h1;
        hnextF[o0 + 128] = h2;
        hnextF[o0 + 192] = h3;
    }

    // ---- optional fused heads (layer 3 only)
    if constexpr (HEADS) {
        const float ws0 = Ws[lane * 2], ws1 = Ws[lane * 2 + 1];
        const float wst = Wst[lane],    wo  = Wo[lane];
        float r[16];
        r[0]  = h0 * ws0; r[1]  = h0 * ws1; r[2]  = h0 * wst; r[3]  = h0 * wo;
        r[4]  = h1 * ws0; r[5]  = h1 * ws1; r[6]  = h1 * wst; r[7]  = h1 * wo;
        r[8]  = h2 * ws0; r[9]  = h2 * ws1; r[10] = h2 * wst; r[11] = h2 * wo;
        r[12] = h3 * ws0; r[13] = h3 * ws1; r[14] = h3 * wst; r[15] = h3 * wo;
#pragma unroll
        for (int off = 1; off < 64; off <<= 1)
#pragma unroll
            for (int t = 0; t < 16; ++t) r[t] += __shfl_xor(r[t], off);
        if (lane == 0) {
            const float bs0 = bs[0], bs1 = bs[1], bt = bst[0], b0 = bo[0];
            float sg = 0.f, oc = 0.f;
#pragma unroll
            for (int i = 0; i < 4; ++i) {
                const size_t n = (size_t)(n0 + i);
                state[n * 2 + 0] = r[i * 4 + 0] + bs0;
                state[n * 2 + 1] = r[i * 4 + 1] + bs1;
                sg += 1.0f / (1.0f + __expf(-(r[i * 4 + 2] + bt)));
                oc += r[i * 4 + 3] + b0;
            }
            red[wv][0] = sg; red[wv][1] = oc;
        }
        __syncthreads();
        if (tid == 0) {
            float a = 0.f, b2 = 0.f;
#pragma unroll
            for (int w = 0; w < 8; ++w) { a += red[w][0]; b2 += red[w][1]; }
            part[blockIdx.x * 2 + 0] = a;
            part[blockIdx.x * 2 + 1] = b2;
        }
    }
}

// ---------------------------------------------------------------- final reduce

__global__ __launch_bounds__(1024) void final_reduce(const float* __restrict__ part,
                                                     float* __restrict__ scal) {
    __shared__ float l0[1024], l1[1024];
    const int t = threadIdx.x;
    float a = 0.f, b = 0.f;
    for (int i = t; i < LAYER_BLOCKS; i += 1024) { a += part[2 * i]; b += part[2 * i + 1]; }
    l0[t] = a; l1[t] = b;
    __syncthreads();
    for (int off = 512; off; off >>= 1) {
        if (t < off) { l0[t] += l0[t + off]; l1[t] += l1[t + off]; }
        __syncthreads();
    }
    if (t == 0) {
        scal[0] = l0[0] / (float)N_NODES;   // stability
        scal[1] = l1[0] / (float)N_NODES;   // opf_cost
    }
}

// ---------------------------------------------------------------- launch

extern "C" void kernel_launch(void* const* d_in, const int* in_sizes, int n_in,
                              void* d_out, int out_size, void* d_ws, size_t ws_size,
                              hipStream_t stream) {
    const float* x   = (const float*)d_in[0];
    const int*   ei  = (const int*)d_in[1];
    const float* W1  = (const float*)d_in[2];
    const float* b1  = (const float*)d_in[3];
    const float* U1  = (const float*)d_in[4];
    const float* c1  = (const float*)d_in[5];
    const float* W2  = (const float*)d_in[6];
    const float* b2  = (const float*)d_in[7];
    const float* U2  = (const float*)d_in[8];
    const float* c2  = (const float*)d_in[9];
    const float* W3  = (const float*)d_in[10];
    const float* b3  = (const float*)d_in[11];
    const float* U3  = (const float*)d_in[12];
    const float* c3  = (const float*)d_in[13];
    const float* Ws  = (const float*)d_in[14];
    const float* bs  = (const float*)d_in[15];
    const float* Wst = (const float*)d_in[16];
    const float* bst = (const float*)d_in[17];
    const float* Wo  = (const float*)d_in[18];
    const float* bo  = (const float*)d_in[19];

    const int* src = ei;              // edge_index[0]
    const int* dst = ei + N_EDGES;    // edge_index[1]

    char* wsp = (char*)d_ws;
    size_t off = 0;
    auto alloc = [&](size_t bytes) -> char* {
        char* p = wsp + off;
        off = (off + bytes + 255) & ~(size_t)255;
        return p;
    };
    unsigned* cnt    = (unsigned*)alloc((size_t)N_NODES * 4);
    float*    invcnt = (float*)   alloc((size_t)N_NODES * 4);
    float*    part   = (float*)   alloc((size_t)LAYER_BLOCKS * 2 * 4);
    float*    V2a    = (float*)   alloc((size_t)5 * 64 * 4);
    float*    V2b    = (float*)   alloc((size_t)64 * 64 * 4);
    float*    V2c    = (float*)   alloc((size_t)64 * 64 * 4);
    float*    cpa    = (float*)   alloc((size_t)64 * 4);
    float*    cpb    = (float*)   alloc((size_t)64 * 4);
    float*    cpc    = (float*)   alloc((size_t)64 * 4);
    unsigned* slots  = (unsigned*)alloc((size_t)N_NODES * SLOTS * 4);   // 19.2 MB
    __half*   h16A   = (__half*)  alloc((size_t)N_NODES * 64 * 2);      // 12.8 MB
    __half*   h16B   = (__half*)  alloc((size_t)N_NODES * 64 * 2);      // 12.8 MB

    float* out   = (float*)d_out;
    float* state = out;                 // [N, 2]
    float* scal  = out + 200000;        // stability, opf_cost
    float* hout  = out + 200002;        // [N, 64]

    const int NB  = (N_NODES + 255) / 256;   // 391
    const int EB8 = (N_EDGES + 2047) / 2048; // 586

    // weight folding (graph-independent)
    precompute_v<5> <<<2, 256, 0, stream>>>(W1, b1, U1, c1, V2a, cpa);
    precompute_v<64><<<17, 256, 0, stream>>>(W2, b2, U2, c2, V2b, cpb);
    precompute_v<64><<<17, 256, 0, stream>>>(W3, b3, U3, c3, V2c, cpc);

    // adjacency: slot array, one batched pass (no scan, no fill)
    zero_u32<<<NB, 256, 0, stream>>>(cnt, N_NODES);
    hist_scatter8<<<EB8, 256, 0, stream>>>(src, dst, cnt, slots);
    invcnt_kernel<<<NB, 256, 0, stream>>>(cnt, invcnt);

    // layers: h = relu(hp@Utop + mean@V2 + cp); fp16 h between layers.
    // L1: fp32 x in (L2-resident), fp16 out. L2: fp16 in/out.
    // L3: fp16 in, fp32 out (d_out) + fused heads.
    fused_layer<5, false, true, false><<<LAYER_BLOCKS, 512, 0, stream>>>(
        x, nullptr, slots, cnt, invcnt, U1, V2a, cpa, nullptr, h16A,
        nullptr, nullptr, nullptr, nullptr, nullptr, nullptr, nullptr, nullptr);
    fused_layer<64, true, true, false><<<LAYER_BLOCKS, 512, 0, stream>>>(
        nullptr, h16A, slots, cnt, invcnt, U2, V2b, cpb, nullptr, h16B,
        nullptr, nullptr, nullptr, nullptr, nullptr, nullptr, nullptr, nullptr);
    fused_layer<64, true, false, true><<<LAYER_BLOCKS, 512, 0, stream>>>(
        nullptr, h16B, slots, cnt, invcnt, U3, V2c, cpc, hout, nullptr,
        Ws, bs, Wst, bst, Wo, bo, state, part);
    final_reduce<<<1, 1024, 0, stream>>>(part, scal);
}